// Round 7
// baseline (49532.880 us; speedup 1.0000x reference)
//
#include <hip/hip_runtime.h>
#include <cmath>

#define BB 64      // batch
#define TT 512     // seq len
#define HH 512     // hidden
#define GG 2048    // 4*H
#define TCH 64     // time chunk
#define LDT 132    // xg_gemm LDS tile row stride (floats)

// ---------------------------------------------------------------------------
// xg GEMM (unchanged — verified correct)
// ---------------------------------------------------------------------------
template<bool GATHER>
__global__ __launch_bounds__(256) void xg_gemm(
    const float* __restrict__ Xsrc, const int* __restrict__ tok,
    const float* __restrict__ Wih, const float* __restrict__ bih,
    const float* __restrict__ bhh, float* __restrict__ XG, int t0)
{
  __shared__ float As[32 * LDT];
  __shared__ float Bs[32 * LDT];
  const int tid = threadIdx.x;
  const int tc = tid & 15, tr = tid >> 4;
  const int m0 = blockIdx.x * 128;
  const int g0 = blockIdx.y * 128;

  float acc[8][8];
#pragma unroll
  for (int i = 0; i < 8; ++i)
#pragma unroll
    for (int j = 0; j < 8; ++j) acc[i][j] = 0.f;

  float4 ra[4], rb[4];
#pragma unroll
  for (int i = 0; i < 4; ++i) {
    const int f = tid + i * 256;
    ra[i] = *(const float4*)&Wih[(size_t)(g0 + (f >> 3)) * HH + ((f & 7) << 2)];
  }
#pragma unroll
  for (int i = 0; i < 4; ++i) {
    const int f = tid + i * 256;
    if (GATHER) {
      const int m = m0 + (f >> 3);
      const int tok_i = tok[(m & 63) * TT + t0 + (m >> 6)];
      rb[i] = *(const float4*)&Xsrc[(size_t)tok_i * HH + ((f & 7) << 2)];
    } else {
      rb[i] = *(const float4*)&Xsrc[((size_t)(t0 + (m0 >> 6) + (f >> 9)) * HH
                                     + ((f >> 4) & 31)) * BB + ((f & 15) << 2)];
    }
  }

  for (int kt = 0; kt < 16; ++kt) {
#pragma unroll
    for (int i = 0; i < 4; ++i) {
      const int f = tid + i * 256;
      const int row = f >> 3, c4 = f & 7, s = c4 & 3;
      const int col = (((row >> 2) ^ s) << 2) + (row & 3);
      As[(c4 * 4 + 0) * LDT + col] = ra[i].x;
      As[(c4 * 4 + 1) * LDT + col] = ra[i].y;
      As[(c4 * 4 + 2) * LDT + col] = ra[i].z;
      As[(c4 * 4 + 3) * LDT + col] = ra[i].w;
    }
#pragma unroll
    for (int i = 0; i < 4; ++i) {
      const int f = tid + i * 256;
      if (GATHER) {
        const int row = f >> 3, c4 = f & 7, s = c4 & 3;
        const int col = (((row >> 2) ^ s) << 2) + (row & 3);
        Bs[(c4 * 4 + 0) * LDT + col] = rb[i].x;
        Bs[(c4 * 4 + 1) * LDT + col] = rb[i].y;
        Bs[(c4 * 4 + 2) * LDT + col] = rb[i].z;
        Bs[(c4 * 4 + 3) * LDT + col] = rb[i].w;
      } else {
        const int kk = (f >> 4) & 31, s = (kk >> 2) & 3;
        const int mq = (((f >> 9) << 4) + (f & 15)) ^ s;
        *(float4*)&Bs[kk * LDT + (mq << 2)] = rb[i];
      }
    }
    __syncthreads();
    if (kt < 15) {
      const int k0 = (kt + 1) * 32;
#pragma unroll
      for (int i = 0; i < 4; ++i) {
        const int f = tid + i * 256;
        ra[i] = *(const float4*)&Wih[(size_t)(g0 + (f >> 3)) * HH + k0 + ((f & 7) << 2)];
      }
#pragma unroll
      for (int i = 0; i < 4; ++i) {
        const int f = tid + i * 256;
        if (GATHER) {
          const int m = m0 + (f >> 3);
          const int tok_i = tok[(m & 63) * TT + t0 + (m >> 6)];
          rb[i] = *(const float4*)&Xsrc[(size_t)tok_i * HH + k0 + ((f & 7) << 2)];
        } else {
          rb[i] = *(const float4*)&Xsrc[((size_t)(t0 + (m0 >> 6) + (f >> 9)) * HH
                                         + k0 + ((f >> 4) & 31)) * BB + ((f & 15) << 2)];
        }
      }
    }
#pragma unroll
    for (int k = 0; k < 32; ++k) {
      const int s = (k >> 2) & 3;
      const float4 a0 = *(const float4*)&As[k * LDT + ((tr ^ s) << 2)];
      const float4 a1 = *(const float4*)&As[k * LDT + ((16 + (tr ^ s)) << 2)];
      const float4 b0 = *(const float4*)&Bs[k * LDT + ((tc ^ s) << 2)];
      const float4 b1 = *(const float4*)&Bs[k * LDT + ((16 + (tc ^ s)) << 2)];
      const float av[8] = {a0.x, a0.y, a0.z, a0.w, a1.x, a1.y, a1.z, a1.w};
      const float bv[8] = {b0.x, b0.y, b0.z, b0.w, b1.x, b1.y, b1.z, b1.w};
#pragma unroll
      for (int i2 = 0; i2 < 8; ++i2)
#pragma unroll
        for (int j2 = 0; j2 < 8; ++j2)
          acc[i2][j2] = fmaf(av[i2], bv[j2], acc[i2][j2]);
    }
    __syncthreads();
  }

#pragma unroll
  for (int ah = 0; ah < 2; ++ah)
#pragma unroll
    for (int i = 0; i < 4; ++i) {
      const int gc = g0 + ah * 64 + tr * 4 + i;
      const float bias = bih[gc] + bhh[gc];
#pragma unroll
      for (int bh = 0; bh < 2; ++bh) {
        const int tl_ = (m0 >> 6) + bh;
        float4 v;
        v.x = acc[ah * 4 + i][bh * 4 + 0] + bias;
        v.y = acc[ah * 4 + i][bh * 4 + 1] + bias;
        v.z = acc[ah * 4 + i][bh * 4 + 2] + bias;
        v.w = acc[ah * 4 + i][bh * 4 + 3] + bias;
        *(float4*)&XG[((size_t)tl_ * GG + gc) * BB + (tc << 2)] = v;
      }
    }
}

// ---------------------------------------------------------------------------
// Persistent recurrence, v5 (= v3 compute core + proven agent-scope sync).
//  - h staging: 4x global_load_dwordx4 sc1 (agent/IF scope — same path the
//    verified __hip_atomic AGENT loads of R4 use, but pipelined: one vmcnt(0)
//    instead of 16 serialized ones).
//  - h store / flag store / flag poll: __hip_atomic_* AGENT relaxed (proven
//    R4/R5). Own-word flag per WG, wave-0 polls all 32 group flags.
// ---------------------------------------------------------------------------
__global__ __launch_bounds__(256, 1) void lstm_chunk(
    const float* __restrict__ XG, const float* __restrict__ Whh,
    float* __restrict__ h0, float* __restrict__ h1,
    float* __restrict__ c, float* __restrict__ Y,
    unsigned* __restrict__ flag, int t0, int l)
{
  const int tid = threadIdx.x;
  const int grp = blockIdx.x & 7;
  const int mid = blockIdx.x >> 3;
  const int rp = tid >> 4;          // 0..15: row within 16
  const int ks = tid & 15;          // 0..15: 32-wide k segment

  __shared__ float4 hs4[8 * 144];
  __shared__ float gs[512];

  // W_hh rows -> registers: thread owns gate rows {q*512 + mid*16 + rp}
  float4 w[4][8];
#pragma unroll
  for (int j = 0; j < 4; ++j)
#pragma unroll
    for (int cc = 0; cc < 8; ++cc)
      w[j][cc] = *(const float4*)&Whh[(size_t)((j << 9) + mid * 16 + rp) * HH
                                      + ks * 32 + cc * 4];

  // c for this chunk in registers (tid<128: one (hc,b) cell each)
  const int hc_l = tid >> 3;
  const int bb_l = tid & 7;
  const int hc_own = mid * 16 + hc_l;
  const int Bg_own = 8 * grp + bb_l;
  float creg = 0.f;
  if (t0 > 0 && tid < 128) creg = c[(size_t)hc_own * BB + Bg_own];

  for (int tl = 0; tl < TCH; ++tl) {
    const int t = t0 + tl;
    const int first = (t == 0) ? 1 : 0;
    const float* h_in = (t & 1) ? h1 : h0;
    float* h_out = (t & 1) ? h0 : h1;

    // XG prefetch (tid<128) — independent of h, overlaps staging latency
    float xgv[4];
    if (tid < 128) {
#pragma unroll
      for (int q = 0; q < 4; ++q)
        xgv[q] = XG[((size_t)tl * GG + (q << 9) + hc_own) * BB + Bg_own];
    }

    float p[4][8];
#pragma unroll
    for (int j = 0; j < 4; ++j)
#pragma unroll
      for (int b = 0; b < 8; ++b) p[j][b] = 0.f;

    if (!first) {
      // ---- stage h slice [8][512] via agent-scope (sc1) vector loads ----
      float4 hv4[4];
#pragma unroll
      for (int i = 0; i < 4; ++i) {
        const int f = tid + i * 256;
        const int b = f >> 7, c4 = f & 127;
        const float* src = &h_in[(size_t)(8 * grp + b) * HH + (c4 << 2)];
        asm volatile("global_load_dwordx4 %0, %1, off sc1"
                     : "=v"(hv4[i]) : "v"(src));
      }
      asm volatile("s_waitcnt vmcnt(0)" ::: "memory");
      __builtin_amdgcn_sched_barrier(0);
#pragma unroll
      for (int i = 0; i < 4; ++i) {
        const int f = tid + i * 256;
        const int b = f >> 7, c4 = f & 127;
        hs4[b * 144 + (c4 >> 3) * 9 + (c4 & 7)] = hv4[i];
      }
      __syncthreads();

      // ---- compute: 4 rows x 32 k vs 8 batches ----
#pragma unroll
      for (int cc = 0; cc < 8; ++cc) {
#pragma unroll
        for (int b = 0; b < 8; ++b) {
          const float4 hv = hs4[b * 144 + ks * 9 + cc];
#pragma unroll
          for (int j = 0; j < 4; ++j) {
            p[j][b] += hv.x * w[j][cc].x + hv.y * w[j][cc].y
                     + hv.z * w[j][cc].z + hv.w * w[j][cc].w;
          }
        }
      }
      // reduce across the 16 ks lanes (tid bits 0..3)
#pragma unroll
      for (int j = 0; j < 4; ++j)
#pragma unroll
        for (int b = 0; b < 8; ++b) {
          float v = p[j][b];
          v += __shfl_xor(v, 1);
          v += __shfl_xor(v, 2);
          v += __shfl_xor(v, 4);
          v += __shfl_xor(v, 8);
          p[j][b] = v;
        }
      if (ks == 0) {
#pragma unroll
        for (int j = 0; j < 4; ++j)
#pragma unroll
          for (int b = 0; b < 8; ++b)
            gs[((j << 4) + rp) * 8 + b] = p[j][b];
      }
    }
    __syncthreads();   // gs ready (or skipped when first)

    // ---- gating ----
    if (tid < 128) {
      float gv[4];
#pragma unroll
      for (int q = 0; q < 4; ++q) {
        float x = xgv[q];
        if (!first) x += gs[(q * 16 + hc_l) * 8 + bb_l];
        gv[q] = x;
      }
      const float cold = first ? 0.f : creg;
      const float si = 1.f / (1.f + expf(-gv[0]));
      const float sf = 1.f / (1.f + expf(-gv[1]));
      const float so = 1.f / (1.f + expf(-gv[3]));
      const float cn = sf * cold + si * tanhf(gv[2]);
      const float hn = so * tanhf(cn);
      creg = cn;
      __hip_atomic_store(&h_out[(size_t)Bg_own * HH + hc_own], hn,
                         __ATOMIC_RELAXED, __HIP_MEMORY_SCOPE_AGENT);
      Y[((size_t)t * HH + hc_own) * BB + Bg_own] = hn;
    }

    // ---- flag barrier: own-word store + wave-0 poll of 32 group flags ----
    asm volatile("s_waitcnt vmcnt(0)" ::: "memory");
    __syncthreads();
    const unsigned sid = (unsigned)(l * TT + t + 1);
    if (tid == 0)
      __hip_atomic_store(&flag[grp * 32 + mid], sid,
                         __ATOMIC_RELAXED, __HIP_MEMORY_SCOPE_AGENT);
    if (tid < 64) {
      const unsigned* fp = &flag[grp * 32 + (tid & 31)];
      while (__any(__hip_atomic_load(fp, __ATOMIC_RELAXED,
                                     __HIP_MEMORY_SCOPE_AGENT) < sid))
        __builtin_amdgcn_s_sleep(1);
    }
    __syncthreads();
  }

  if (tid < 128) c[(size_t)hc_own * BB + Bg_own] = creg;
}

// ---------------------------------------------------------------------------
__global__ __launch_bounds__(64) void cls_kernel(
    const float* __restrict__ Y, const float* __restrict__ Wcls,
    const float* __restrict__ bcls, float* __restrict__ out)
{
  __shared__ float feat[512];
  const int b = blockIdx.x, tid = threadIdx.x;
  for (int k = tid; k < HH; k += 64)
    feat[k] = Y[((size_t)(TT - 1) * HH + k) * BB + b];
  __syncthreads();
  if (tid < 20) {
    float acc = bcls[tid];
    for (int k = 0; k < HH; ++k) acc = fmaf(feat[k], Wcls[tid * HH + k], acc);
    out[b * 20 + tid] = acc;
  }
}

// ---------------------------------------------------------------------------
extern "C" void kernel_launch(void* const* d_in, const int* in_sizes, int n_in,
                              void* d_out, int out_size, void* d_ws, size_t ws_size,
                              hipStream_t stream) {
  (void)in_sizes; (void)n_in; (void)out_size; (void)ws_size;
  const int*   tok  = (const int*)d_in[0];
  const float* emb  = (const float*)d_in[1];
  const float* Wih  = (const float*)d_in[2];
  const float* Whh  = (const float*)d_in[3];
  const float* bih  = (const float*)d_in[4];
  const float* bhh  = (const float*)d_in[5];
  const float* Wcls = (const float*)d_in[6];
  const float* bcls = (const float*)d_in[7];
  float* out = (float*)d_out;

  // ws: Y [T][H][B] | XG [TCH][4H][B] | h0 | h1 | c | flag(256 words)
  float* Y  = (float*)d_ws;
  float* XG = Y + (size_t)TT * HH * BB;
  float* h0 = XG + (size_t)TCH * GG * BB;
  float* h1 = h0 + (size_t)BB * HH;
  float* c  = h1 + (size_t)BB * HH;
  unsigned* flag = (unsigned*)(c + (size_t)HH * BB);

  hipMemsetAsync(flag, 0, 256 * sizeof(unsigned), stream);

  for (int l = 0; l < 5; ++l) {
    const float* wih_l = Wih + (size_t)l * GG * HH;
    const float* whh_l = Whh + (size_t)l * GG * HH;
    const float* bih_l = bih + (size_t)l * GG;
    const float* bhh_l = bhh + (size_t)l * GG;
    for (int t0 = 0; t0 < TT; t0 += TCH) {
      if (l == 0)
        xg_gemm<true><<<dim3(32, 16), 256, 0, stream>>>(emb, tok, wih_l, bih_l, bhh_l, XG, t0);
      else
        xg_gemm<false><<<dim3(32, 16), 256, 0, stream>>>(Y, nullptr, wih_l, bih_l, bhh_l, XG, t0);
      lstm_chunk<<<256, 256, 0, stream>>>(XG, whh_l, h0, h1, c, Y, flag, t0, l);
    }
  }
  cls_kernel<<<64, 64, 0, stream>>>(Y, Wcls, bcls, out);
}

// Round 8
// 48439.911 us; speedup vs baseline: 1.0226x; 1.0226x over previous
//
#include <hip/hip_runtime.h>
#include <cmath>

#define BB 64      // batch
#define TT 512     // seq len
#define HH 512     // hidden
#define GG 2048    // 4*H
#define TCH 64     // time chunk
#define LDT 132    // xg_gemm LDS tile row stride (floats)

// ---------------------------------------------------------------------------
// xg GEMM (unchanged — verified correct)
// ---------------------------------------------------------------------------
template<bool GATHER>
__global__ __launch_bounds__(256) void xg_gemm(
    const float* __restrict__ Xsrc, const int* __restrict__ tok,
    const float* __restrict__ Wih, const float* __restrict__ bih,
    const float* __restrict__ bhh, float* __restrict__ XG, int t0)
{
  __shared__ float As[32 * LDT];
  __shared__ float Bs[32 * LDT];
  const int tid = threadIdx.x;
  const int tc = tid & 15, tr = tid >> 4;
  const int m0 = blockIdx.x * 128;
  const int g0 = blockIdx.y * 128;

  float acc[8][8];
#pragma unroll
  for (int i = 0; i < 8; ++i)
#pragma unroll
    for (int j = 0; j < 8; ++j) acc[i][j] = 0.f;

  float4 ra[4], rb[4];
#pragma unroll
  for (int i = 0; i < 4; ++i) {
    const int f = tid + i * 256;
    ra[i] = *(const float4*)&Wih[(size_t)(g0 + (f >> 3)) * HH + ((f & 7) << 2)];
  }
#pragma unroll
  for (int i = 0; i < 4; ++i) {
    const int f = tid + i * 256;
    if (GATHER) {
      const int m = m0 + (f >> 3);
      const int tok_i = tok[(m & 63) * TT + t0 + (m >> 6)];
      rb[i] = *(const float4*)&Xsrc[(size_t)tok_i * HH + ((f & 7) << 2)];
    } else {
      rb[i] = *(const float4*)&Xsrc[((size_t)(t0 + (m0 >> 6) + (f >> 9)) * HH
                                     + ((f >> 4) & 31)) * BB + ((f & 15) << 2)];
    }
  }

  for (int kt = 0; kt < 16; ++kt) {
#pragma unroll
    for (int i = 0; i < 4; ++i) {
      const int f = tid + i * 256;
      const int row = f >> 3, c4 = f & 7, s = c4 & 3;
      const int col = (((row >> 2) ^ s) << 2) + (row & 3);
      As[(c4 * 4 + 0) * LDT + col] = ra[i].x;
      As[(c4 * 4 + 1) * LDT + col] = ra[i].y;
      As[(c4 * 4 + 2) * LDT + col] = ra[i].z;
      As[(c4 * 4 + 3) * LDT + col] = ra[i].w;
    }
#pragma unroll
    for (int i = 0; i < 4; ++i) {
      const int f = tid + i * 256;
      if (GATHER) {
        const int row = f >> 3, c4 = f & 7, s = c4 & 3;
        const int col = (((row >> 2) ^ s) << 2) + (row & 3);
        Bs[(c4 * 4 + 0) * LDT + col] = rb[i].x;
        Bs[(c4 * 4 + 1) * LDT + col] = rb[i].y;
        Bs[(c4 * 4 + 2) * LDT + col] = rb[i].z;
        Bs[(c4 * 4 + 3) * LDT + col] = rb[i].w;
      } else {
        const int kk = (f >> 4) & 31, s = (kk >> 2) & 3;
        const int mq = (((f >> 9) << 4) + (f & 15)) ^ s;
        *(float4*)&Bs[kk * LDT + (mq << 2)] = rb[i];
      }
    }
    __syncthreads();
    if (kt < 15) {
      const int k0 = (kt + 1) * 32;
#pragma unroll
      for (int i = 0; i < 4; ++i) {
        const int f = tid + i * 256;
        ra[i] = *(const float4*)&Wih[(size_t)(g0 + (f >> 3)) * HH + k0 + ((f & 7) << 2)];
      }
#pragma unroll
      for (int i = 0; i < 4; ++i) {
        const int f = tid + i * 256;
        if (GATHER) {
          const int m = m0 + (f >> 3);
          const int tok_i = tok[(m & 63) * TT + t0 + (m >> 6)];
          rb[i] = *(const float4*)&Xsrc[(size_t)tok_i * HH + k0 + ((f & 7) << 2)];
        } else {
          rb[i] = *(const float4*)&Xsrc[((size_t)(t0 + (m0 >> 6) + (f >> 9)) * HH
                                         + k0 + ((f >> 4) & 31)) * BB + ((f & 15) << 2)];
        }
      }
    }
#pragma unroll
    for (int k = 0; k < 32; ++k) {
      const int s = (k >> 2) & 3;
      const float4 a0 = *(const float4*)&As[k * LDT + ((tr ^ s) << 2)];
      const float4 a1 = *(const float4*)&As[k * LDT + ((16 + (tr ^ s)) << 2)];
      const float4 b0 = *(const float4*)&Bs[k * LDT + ((tc ^ s) << 2)];
      const float4 b1 = *(const float4*)&Bs[k * LDT + ((16 + (tc ^ s)) << 2)];
      const float av[8] = {a0.x, a0.y, a0.z, a0.w, a1.x, a1.y, a1.z, a1.w};
      const float bv[8] = {b0.x, b0.y, b0.z, b0.w, b1.x, b1.y, b1.z, b1.w};
#pragma unroll
      for (int i2 = 0; i2 < 8; ++i2)
#pragma unroll
        for (int j2 = 0; j2 < 8; ++j2)
          acc[i2][j2] = fmaf(av[i2], bv[j2], acc[i2][j2]);
    }
    __syncthreads();
  }

#pragma unroll
  for (int ah = 0; ah < 2; ++ah)
#pragma unroll
    for (int i = 0; i < 4; ++i) {
      const int gc = g0 + ah * 64 + tr * 4 + i;
      const float bias = bih[gc] + bhh[gc];
#pragma unroll
      for (int bh = 0; bh < 2; ++bh) {
        const int tl_ = (m0 >> 6) + bh;
        float4 v;
        v.x = acc[ah * 4 + i][bh * 4 + 0] + bias;
        v.y = acc[ah * 4 + i][bh * 4 + 1] + bias;
        v.z = acc[ah * 4 + i][bh * 4 + 2] + bias;
        v.w = acc[ah * 4 + i][bh * 4 + 3] + bias;
        *(float4*)&XG[((size_t)tl_ * GG + gc) * BB + (tc << 2)] = v;
      }
    }
}

// ---------------------------------------------------------------------------
// Persistent recurrence, v6 = R4's proven sync + R5's compute core + one fix:
// stage h by issuing ALL 16 relaxed-agent atomic loads into registers first,
// THEN the 4 LDS writes (one vmcnt drain instead of 16 serialized RTTs).
// Barrier: R4's exact fetch_add + tid0 single-word spin + s_sleep(2) —
// the only config measured with zero outlier dispatches.
// ---------------------------------------------------------------------------
__global__ __launch_bounds__(256, 1) void lstm_chunk(
    const float* __restrict__ XG, const float* __restrict__ Whh,
    float* __restrict__ h0, float* __restrict__ h1,
    float* __restrict__ c, float* __restrict__ Y,
    unsigned* __restrict__ bar, int t0, int l)
{
  const int tid = threadIdx.x;
  const int grp = blockIdx.x & 7;
  const int mid = blockIdx.x >> 3;
  const int rp = tid >> 4;          // 0..15: row within 16
  const int ks = tid & 15;          // 0..15: 32-wide k segment

  __shared__ float4 hs4[8 * 144];
  __shared__ float gs[512];

  // W_hh rows -> registers: thread owns gate rows {q*512 + mid*16 + rp}
  float4 w[4][8];
#pragma unroll
  for (int j = 0; j < 4; ++j)
#pragma unroll
    for (int cc = 0; cc < 8; ++cc)
      w[j][cc] = *(const float4*)&Whh[(size_t)((j << 9) + mid * 16 + rp) * HH
                                      + ks * 32 + cc * 4];

  // c for this chunk in registers (tid<128: one (hc,b) cell each)
  const int hc_l = tid >> 3;
  const int bb_l = tid & 7;
  const int hc_own = mid * 16 + hc_l;
  const int Bg_own = 8 * grp + bb_l;
  float creg = 0.f;
  if (t0 > 0 && tid < 128) creg = c[(size_t)hc_own * BB + Bg_own];

  for (int tl = 0; tl < TCH; ++tl) {
    const int t = t0 + tl;
    const int first = (t == 0) ? 1 : 0;
    const float* h_in = (t & 1) ? h1 : h0;
    float* h_out = (t & 1) ? h0 : h1;

    // XG prefetch (tid<128) — independent of h, overlaps staging latency
    float xgv[4];
    if (tid < 128) {
#pragma unroll
      for (int q = 0; q < 4; ++q)
        xgv[q] = XG[((size_t)tl * GG + (q << 9) + hc_own) * BB + Bg_own];
    }

    float p[4][8];
#pragma unroll
    for (int j = 0; j < 4; ++j)
#pragma unroll
      for (int b = 0; b < 8; ++b) p[j][b] = 0.f;

    if (!first) {
      // ---- stage h slice [8][512]: ALL loads first, then LDS writes ----
      float hv[16];
#pragma unroll
      for (int i = 0; i < 4; ++i) {
        const int f = tid + i * 256;
        const int b = f >> 7, c4 = f & 127;
        const float* src = &h_in[(size_t)(8 * grp + b) * HH + (c4 << 2)];
        hv[i * 4 + 0] = __hip_atomic_load(src + 0, __ATOMIC_RELAXED, __HIP_MEMORY_SCOPE_AGENT);
        hv[i * 4 + 1] = __hip_atomic_load(src + 1, __ATOMIC_RELAXED, __HIP_MEMORY_SCOPE_AGENT);
        hv[i * 4 + 2] = __hip_atomic_load(src + 2, __ATOMIC_RELAXED, __HIP_MEMORY_SCOPE_AGENT);
        hv[i * 4 + 3] = __hip_atomic_load(src + 3, __ATOMIC_RELAXED, __HIP_MEMORY_SCOPE_AGENT);
      }
#pragma unroll
      for (int i = 0; i < 4; ++i) {
        const int f = tid + i * 256;
        const int b = f >> 7, c4 = f & 127;
        float4 v;
        v.x = hv[i * 4 + 0]; v.y = hv[i * 4 + 1];
        v.z = hv[i * 4 + 2]; v.w = hv[i * 4 + 3];
        hs4[b * 144 + (c4 >> 3) * 9 + (c4 & 7)] = v;
      }
      __syncthreads();

      // ---- compute: 4 rows x 32 k vs 8 batches ----
#pragma unroll
      for (int cc = 0; cc < 8; ++cc) {
#pragma unroll
        for (int b = 0; b < 8; ++b) {
          const float4 hv2 = hs4[b * 144 + ks * 9 + cc];
#pragma unroll
          for (int j = 0; j < 4; ++j) {
            p[j][b] += hv2.x * w[j][cc].x + hv2.y * w[j][cc].y
                     + hv2.z * w[j][cc].z + hv2.w * w[j][cc].w;
          }
        }
      }
      // reduce across the 16 ks lanes (tid bits 0..3)
#pragma unroll
      for (int j = 0; j < 4; ++j)
#pragma unroll
        for (int b = 0; b < 8; ++b) {
          float v = p[j][b];
          v += __shfl_xor(v, 1);
          v += __shfl_xor(v, 2);
          v += __shfl_xor(v, 4);
          v += __shfl_xor(v, 8);
          p[j][b] = v;
        }
      if (ks == 0) {
#pragma unroll
        for (int j = 0; j < 4; ++j)
#pragma unroll
          for (int b = 0; b < 8; ++b)
            gs[((j << 4) + rp) * 8 + b] = p[j][b];
      }
    }
    __syncthreads();   // gs ready (or skipped when first)

    // ---- gating ----
    if (tid < 128) {
      float gv[4];
#pragma unroll
      for (int q = 0; q < 4; ++q) {
        float x = xgv[q];
        if (!first) x += gs[(q * 16 + hc_l) * 8 + bb_l];
        gv[q] = x;
      }
      const float cold = first ? 0.f : creg;
      const float si = 1.f / (1.f + expf(-gv[0]));
      const float sf = 1.f / (1.f + expf(-gv[1]));
      const float so = 1.f / (1.f + expf(-gv[3]));
      const float cn = sf * cold + si * tanhf(gv[2]);
      const float hn = so * tanhf(cn);
      creg = cn;
      __hip_atomic_store(&h_out[(size_t)Bg_own * HH + hc_own], hn,
                         __ATOMIC_RELAXED, __HIP_MEMORY_SCOPE_AGENT);
      Y[((size_t)t * HH + hc_own) * BB + Bg_own] = hn;
    }

    // ---- group barrier (R4-exact): stores acked, then one counter word ----
    asm volatile("s_waitcnt vmcnt(0)" ::: "memory");
    __syncthreads();
    if (tid == 0) {
      __hip_atomic_fetch_add(&bar[grp * 32], 1u, __ATOMIC_RELAXED, __HIP_MEMORY_SCOPE_AGENT);
      const unsigned tgt = 32u * (unsigned)(l * 512 + t + 1);
      while (__hip_atomic_load(&bar[grp * 32], __ATOMIC_RELAXED, __HIP_MEMORY_SCOPE_AGENT) < tgt)
        __builtin_amdgcn_s_sleep(2);
    }
    __syncthreads();
  }

  if (tid < 128) c[(size_t)hc_own * BB + Bg_own] = creg;
}

// ---------------------------------------------------------------------------
__global__ __launch_bounds__(64) void cls_kernel(
    const float* __restrict__ Y, const float* __restrict__ Wcls,
    const float* __restrict__ bcls, float* __restrict__ out)
{
  __shared__ float feat[512];
  const int b = blockIdx.x, tid = threadIdx.x;
  for (int k = tid; k < HH; k += 64)
    feat[k] = Y[((size_t)(TT - 1) * HH + k) * BB + b];
  __syncthreads();
  if (tid < 20) {
    float acc = bcls[tid];
    for (int k = 0; k < HH; ++k) acc = fmaf(feat[k], Wcls[tid * HH + k], acc);
    out[b * 20 + tid] = acc;
  }
}

// ---------------------------------------------------------------------------
extern "C" void kernel_launch(void* const* d_in, const int* in_sizes, int n_in,
                              void* d_out, int out_size, void* d_ws, size_t ws_size,
                              hipStream_t stream) {
  (void)in_sizes; (void)n_in; (void)out_size; (void)ws_size;
  const int*   tok  = (const int*)d_in[0];
  const float* emb  = (const float*)d_in[1];
  const float* Wih  = (const float*)d_in[2];
  const float* Whh  = (const float*)d_in[3];
  const float* bih  = (const float*)d_in[4];
  const float* bhh  = (const float*)d_in[5];
  const float* Wcls = (const float*)d_in[6];
  const float* bcls = (const float*)d_in[7];
  float* out = (float*)d_out;

  // ws: Y [T][H][B] | XG [TCH][4H][B] | h0 | h1 | c | bar(256 words)
  float* Y  = (float*)d_ws;
  float* XG = Y + (size_t)TT * HH * BB;
  float* h0 = XG + (size_t)TCH * GG * BB;
  float* h1 = h0 + (size_t)BB * HH;
  float* c  = h1 + (size_t)BB * HH;
  unsigned* bar = (unsigned*)(c + (size_t)HH * BB);

  hipMemsetAsync(bar, 0, 256 * sizeof(unsigned), stream);

  for (int l = 0; l < 5; ++l) {
    const float* wih_l = Wih + (size_t)l * GG * HH;
    const float* whh_l = Whh + (size_t)l * GG * HH;
    const float* bih_l = bih + (size_t)l * GG;
    const float* bhh_l = bhh + (size_t)l * GG;
    for (int t0 = 0; t0 < TT; t0 += TCH) {
      if (l == 0)
        xg_gemm<true><<<dim3(32, 16), 256, 0, stream>>>(emb, tok, wih_l, bih_l, bhh_l, XG, t0);
      else
        xg_gemm<false><<<dim3(32, 16), 256, 0, stream>>>(Y, nullptr, wih_l, bih_l, bhh_l, XG, t0);
      lstm_chunk<<<256, 256, 0, stream>>>(XG, whh_l, h0, h1, c, Y, bar, t0, l);
    }
  }
  cls_kernel<<<64, 64, 0, stream>>>(Y, Wcls, bcls, out);
}

// Round 9
// 33021.713 us; speedup vs baseline: 1.5000x; 1.4669x over previous
//
#include <hip/hip_runtime.h>
#include <cmath>

#define BB 64      // batch
#define TT 512     // seq len
#define HH 512     // hidden
#define GG 2048    // 4*H
#define TCH 64     // time chunk
#define LDT 132    // xg_gemm LDS tile row stride (floats)

// ---------------------------------------------------------------------------
// xg GEMM (unchanged — verified correct)
// ---------------------------------------------------------------------------
template<bool GATHER>
__global__ __launch_bounds__(256) void xg_gemm(
    const float* __restrict__ Xsrc, const int* __restrict__ tok,
    const float* __restrict__ Wih, const float* __restrict__ bih,
    const float* __restrict__ bhh, float* __restrict__ XG, int t0)
{
  __shared__ float As[32 * LDT];
  __shared__ float Bs[32 * LDT];
  const int tid = threadIdx.x;
  const int tc = tid & 15, tr = tid >> 4;
  const int m0 = blockIdx.x * 128;
  const int g0 = blockIdx.y * 128;

  float acc[8][8];
#pragma unroll
  for (int i = 0; i < 8; ++i)
#pragma unroll
    for (int j = 0; j < 8; ++j) acc[i][j] = 0.f;

  float4 ra[4], rb[4];
#pragma unroll
  for (int i = 0; i < 4; ++i) {
    const int f = tid + i * 256;
    ra[i] = *(const float4*)&Wih[(size_t)(g0 + (f >> 3)) * HH + ((f & 7) << 2)];
  }
#pragma unroll
  for (int i = 0; i < 4; ++i) {
    const int f = tid + i * 256;
    if (GATHER) {
      const int m = m0 + (f >> 3);
      const int tok_i = tok[(m & 63) * TT + t0 + (m >> 6)];
      rb[i] = *(const float4*)&Xsrc[(size_t)tok_i * HH + ((f & 7) << 2)];
    } else {
      rb[i] = *(const float4*)&Xsrc[((size_t)(t0 + (m0 >> 6) + (f >> 9)) * HH
                                     + ((f >> 4) & 31)) * BB + ((f & 15) << 2)];
    }
  }

  for (int kt = 0; kt < 16; ++kt) {
#pragma unroll
    for (int i = 0; i < 4; ++i) {
      const int f = tid + i * 256;
      const int row = f >> 3, c4 = f & 7, s = c4 & 3;
      const int col = (((row >> 2) ^ s) << 2) + (row & 3);
      As[(c4 * 4 + 0) * LDT + col] = ra[i].x;
      As[(c4 * 4 + 1) * LDT + col] = ra[i].y;
      As[(c4 * 4 + 2) * LDT + col] = ra[i].z;
      As[(c4 * 4 + 3) * LDT + col] = ra[i].w;
    }
#pragma unroll
    for (int i = 0; i < 4; ++i) {
      const int f = tid + i * 256;
      if (GATHER) {
        const int row = f >> 3, c4 = f & 7, s = c4 & 3;
        const int col = (((row >> 2) ^ s) << 2) + (row & 3);
        Bs[(c4 * 4 + 0) * LDT + col] = rb[i].x;
        Bs[(c4 * 4 + 1) * LDT + col] = rb[i].y;
        Bs[(c4 * 4 + 2) * LDT + col] = rb[i].z;
        Bs[(c4 * 4 + 3) * LDT + col] = rb[i].w;
      } else {
        const int kk = (f >> 4) & 31, s = (kk >> 2) & 3;
        const int mq = (((f >> 9) << 4) + (f & 15)) ^ s;
        *(float4*)&Bs[kk * LDT + (mq << 2)] = rb[i];
      }
    }
    __syncthreads();
    if (kt < 15) {
      const int k0 = (kt + 1) * 32;
#pragma unroll
      for (int i = 0; i < 4; ++i) {
        const int f = tid + i * 256;
        ra[i] = *(const float4*)&Wih[(size_t)(g0 + (f >> 3)) * HH + k0 + ((f & 7) << 2)];
      }
#pragma unroll
      for (int i = 0; i < 4; ++i) {
        const int f = tid + i * 256;
        if (GATHER) {
          const int m = m0 + (f >> 3);
          const int tok_i = tok[(m & 63) * TT + t0 + (m >> 6)];
          rb[i] = *(const float4*)&Xsrc[(size_t)tok_i * HH + k0 + ((f & 7) << 2)];
        } else {
          rb[i] = *(const float4*)&Xsrc[((size_t)(t0 + (m0 >> 6) + (f >> 9)) * HH
                                         + k0 + ((f >> 4) & 31)) * BB + ((f & 15) << 2)];
        }
      }
    }
#pragma unroll
    for (int k = 0; k < 32; ++k) {
      const int s = (k >> 2) & 3;
      const float4 a0 = *(const float4*)&As[k * LDT + ((tr ^ s) << 2)];
      const float4 a1 = *(const float4*)&As[k * LDT + ((16 + (tr ^ s)) << 2)];
      const float4 b0 = *(const float4*)&Bs[k * LDT + ((tc ^ s) << 2)];
      const float4 b1 = *(const float4*)&Bs[k * LDT + ((16 + (tc ^ s)) << 2)];
      const float av[8] = {a0.x, a0.y, a0.z, a0.w, a1.x, a1.y, a1.z, a1.w};
      const float bv[8] = {b0.x, b0.y, b0.z, b0.w, b1.x, b1.y, b1.z, b1.w};
#pragma unroll
      for (int i2 = 0; i2 < 8; ++i2)
#pragma unroll
        for (int j2 = 0; j2 < 8; ++j2)
          acc[i2][j2] = fmaf(av[i2], bv[j2], acc[i2][j2]);
    }
    __syncthreads();
  }

#pragma unroll
  for (int ah = 0; ah < 2; ++ah)
#pragma unroll
    for (int i = 0; i < 4; ++i) {
      const int gc = g0 + ah * 64 + tr * 4 + i;
      const float bias = bih[gc] + bhh[gc];
#pragma unroll
      for (int bh = 0; bh < 2; ++bh) {
        const int tl_ = (m0 >> 6) + bh;
        float4 v;
        v.x = acc[ah * 4 + i][bh * 4 + 0] + bias;
        v.y = acc[ah * 4 + i][bh * 4 + 1] + bias;
        v.z = acc[ah * 4 + i][bh * 4 + 2] + bias;
        v.w = acc[ah * 4 + i][bh * 4 + 3] + bias;
        *(float4*)&XG[((size_t)tl_ * GG + gc) * BB + (tc << 2)] = v;
      }
    }
}

// ---------------------------------------------------------------------------
__device__ __forceinline__ float4 ld4a(const float* src) {
  float4 v;
  v.x = __hip_atomic_load(src + 0, __ATOMIC_RELAXED, __HIP_MEMORY_SCOPE_AGENT);
  v.y = __hip_atomic_load(src + 1, __ATOMIC_RELAXED, __HIP_MEMORY_SCOPE_AGENT);
  v.z = __hip_atomic_load(src + 2, __ATOMIC_RELAXED, __HIP_MEMORY_SCOPE_AGENT);
  v.w = __hip_atomic_load(src + 3, __ATOMIC_RELAXED, __HIP_MEMORY_SCOPE_AGENT);
  return v;
}

// ---------------------------------------------------------------------------
// Persistent recurrence, v7 = R4's exact low-pressure core (w0/w1 2-row,
// p0/p1, 16-cc loop, XG read in gating — no remat cliff) with two fixes:
//  (1) depth-2 pipelined staging: two float4 load-groups in flight before
//      first LDS write (MLP ~8 dwords/wave vs ~4), +8 VGPRs only.
//  (2) parallel flag barrier: 32 WGs store 32 separate words (1 parallel
//      IF RTT vs 32 serialized fetch_adds), per-lane poll + s_sleep(4).
// ---------------------------------------------------------------------------
__global__ __launch_bounds__(256, 1) void lstm_chunk(
    const float* __restrict__ XG, const float* __restrict__ Whh,
    float* __restrict__ h0, float* __restrict__ h1,
    float* __restrict__ c, float* __restrict__ Y,
    unsigned* __restrict__ flag, int t0, int l)
{
  const int tid = threadIdx.x;
  const int grp = blockIdx.x & 7;
  const int mid = blockIdx.x >> 3;
  const int rp = tid >> 3;          // 0..31: row pair
  const int ks = tid & 7;           // 0..7: 64-wide k segment
  const int lr0 = 2 * rp, lr1 = 2 * rp + 1;   // local rows (q*16 + i)
  const int gc0 = ((lr0 >> 4) << 9) + mid * 16 + (lr0 & 15);
  const int gc1 = ((lr1 >> 4) << 9) + mid * 16 + (lr1 & 15);

  __shared__ float4 hs4[8 * 136];
  __shared__ float gs[512];

  // W_hh rows -> registers (once per launch)
  float4 w0[16], w1[16];
#pragma unroll
  for (int cc = 0; cc < 16; ++cc) {
    w0[cc] = *(const float4*)&Whh[(size_t)gc0 * HH + ks * 64 + cc * 4];
    w1[cc] = *(const float4*)&Whh[(size_t)gc1 * HH + ks * 64 + cc * 4];
  }

  // c for this chunk in registers (tid<128: one (hc,b) cell each)
  const int hc_l = tid >> 3;
  const int bb_l = tid & 7;
  const int hc_own = mid * 16 + hc_l;
  const int Bg_own = 8 * grp + bb_l;
  float creg = 0.f;
  if (t0 > 0 && tid < 128) creg = c[(size_t)hc_own * BB + Bg_own];

  // staging geometry: row b_i = (tid>>7) + 2i, float4-col c4 = tid&127
  const int sb = tid >> 7;            // 0 or 1
  const int sc4 = tid & 127;          // float4 column
  const int lds_i = sc4 + (sc4 >> 4); // rotated col index

  for (int tl = 0; tl < TCH; ++tl) {
    const int t = t0 + tl;
    const int first = (t == 0) ? 1 : 0;
    const float* h_in = (t & 1) ? h1 : h0;
    float* h_out = (t & 1) ? h0 : h1;

    if (!first) {
      // ---- stage h slice [8][512]: depth-2 software pipeline ----
      const float* s0 = &h_in[(size_t)(8 * grp + sb + 0) * HH + (sc4 << 2)];
      const float* s1 = &h_in[(size_t)(8 * grp + sb + 2) * HH + (sc4 << 2)];
      const float* s2 = &h_in[(size_t)(8 * grp + sb + 4) * HH + (sc4 << 2)];
      const float* s3 = &h_in[(size_t)(8 * grp + sb + 6) * HH + (sc4 << 2)];
      float4 va = ld4a(s0);
      float4 vb = ld4a(s1);
      hs4[(sb + 0) * 136 + lds_i] = va;
      va = ld4a(s2);
      hs4[(sb + 2) * 136 + lds_i] = vb;
      vb = ld4a(s3);
      hs4[(sb + 4) * 136 + lds_i] = va;
      hs4[(sb + 6) * 136 + lds_i] = vb;
      __syncthreads();

      // ---- compute: 2 rows x 64 k vs 8 batches (R4-exact) ----
      float p0[8], p1[8];
#pragma unroll
      for (int b = 0; b < 8; ++b) { p0[b] = 0.f; p1[b] = 0.f; }
#pragma unroll
      for (int cc = 0; cc < 16; ++cc) {
#pragma unroll
        for (int b = 0; b < 8; ++b) {
          const float4 hv = hs4[b * 136 + 17 * ks + cc];
          p0[b] += hv.x * w0[cc].x + hv.y * w0[cc].y + hv.z * w0[cc].z + hv.w * w0[cc].w;
          p1[b] += hv.x * w1[cc].x + hv.y * w1[cc].y + hv.z * w1[cc].z + hv.w * w1[cc].w;
        }
      }
      // reduce across the 8 ks lanes (tid bits 0..2)
#pragma unroll
      for (int b = 0; b < 8; ++b) {
        float v0 = p0[b], v1 = p1[b];
        v0 += __shfl_xor(v0, 1, 64); v0 += __shfl_xor(v0, 2, 64); v0 += __shfl_xor(v0, 4, 64);
        v1 += __shfl_xor(v1, 1, 64); v1 += __shfl_xor(v1, 2, 64); v1 += __shfl_xor(v1, 4, 64);
        p0[b] = v0; p1[b] = v1;
      }
      if (ks == 0) {
#pragma unroll
        for (int b = 0; b < 8; ++b) {
          gs[lr0 * 8 + b] = p0[b];
          gs[lr1 * 8 + b] = p1[b];
        }
      }
    }
    __syncthreads();   // gs ready (or skipped when first)

    // ---- gating (R4-exact: XG read here, short liveness) ----
    if (tid < 128) {
      float gv[4];
#pragma unroll
      for (int q = 0; q < 4; ++q) {
        const int gc = (q << 9) + hc_own;
        float x = XG[((size_t)tl * GG + gc) * BB + Bg_own];
        if (!first) x += gs[(q * 16 + hc_l) * 8 + bb_l];
        gv[q] = x;
      }
      const float cold = first ? 0.f : creg;
      const float si = 1.f / (1.f + expf(-gv[0]));
      const float sf = 1.f / (1.f + expf(-gv[1]));
      const float so = 1.f / (1.f + expf(-gv[3]));
      const float cn = sf * cold + si * tanhf(gv[2]);
      const float hn = so * tanhf(cn);
      creg = cn;
      __hip_atomic_store(&h_out[(size_t)Bg_own * HH + hc_own], hn,
                         __ATOMIC_RELAXED, __HIP_MEMORY_SCOPE_AGENT);
      Y[((size_t)t * HH + hc_own) * BB + Bg_own] = hn;
    }

    // ---- parallel flag barrier ----
    asm volatile("s_waitcnt vmcnt(0)" ::: "memory");   // own h stores acked
    __syncthreads();                                   // => all WG stores acked
    const unsigned sid = (unsigned)(l * TT + t + 1);
    if (tid == 0)
      __hip_atomic_store(&flag[(grp << 5) + mid], sid,
                         __ATOMIC_RELAXED, __HIP_MEMORY_SCOPE_AGENT);
    if (tid < 32) {
      const unsigned* fp = &flag[(grp << 5) + tid];
      while (__hip_atomic_load(fp, __ATOMIC_RELAXED, __HIP_MEMORY_SCOPE_AGENT) < sid)
        __builtin_amdgcn_s_sleep(4);
    }
    __syncthreads();
  }

  if (tid < 128) c[(size_t)hc_own * BB + Bg_own] = creg;
}

// ---------------------------------------------------------------------------
__global__ __launch_bounds__(64) void cls_kernel(
    const float* __restrict__ Y, const float* __restrict__ Wcls,
    const float* __restrict__ bcls, float* __restrict__ out)
{
  __shared__ float feat[512];
  const int b = blockIdx.x, tid = threadIdx.x;
  for (int k = tid; k < HH; k += 64)
    feat[k] = Y[((size_t)(TT - 1) * HH + k) * BB + b];
  __syncthreads();
  if (tid < 20) {
    float acc = bcls[tid];
    for (int k = 0; k < HH; ++k) acc = fmaf(feat[k], Wcls[tid * HH + k], acc);
    out[b * 20 + tid] = acc;
  }
}

// ---------------------------------------------------------------------------
extern "C" void kernel_launch(void* const* d_in, const int* in_sizes, int n_in,
                              void* d_out, int out_size, void* d_ws, size_t ws_size,
                              hipStream_t stream) {
  (void)in_sizes; (void)n_in; (void)out_size; (void)ws_size;
  const int*   tok  = (const int*)d_in[0];
  const float* emb  = (const float*)d_in[1];
  const float* Wih  = (const float*)d_in[2];
  const float* Whh  = (const float*)d_in[3];
  const float* bih  = (const float*)d_in[4];
  const float* bhh  = (const float*)d_in[5];
  const float* Wcls = (const float*)d_in[6];
  const float* bcls = (const float*)d_in[7];
  float* out = (float*)d_out;

  // ws: Y [T][H][B] | XG [TCH][4H][B] | h0 | h1 | c | flag(256 words)
  float* Y  = (float*)d_ws;
  float* XG = Y + (size_t)TT * HH * BB;
  float* h0 = XG + (size_t)TCH * GG * BB;
  float* h1 = h0 + (size_t)BB * HH;
  float* c  = h1 + (size_t)BB * HH;
  unsigned* flag = (unsigned*)(c + (size_t)HH * BB);

  hipMemsetAsync(flag, 0, 256 * sizeof(unsigned), stream);

  for (int l = 0; l < 5; ++l) {
    const float* wih_l = Wih + (size_t)l * GG * HH;
    const float* whh_l = Whh + (size_t)l * GG * HH;
    const float* bih_l = bih + (size_t)l * GG;
    const float* bhh_l = bhh + (size_t)l * GG;
    for (int t0 = 0; t0 < TT; t0 += TCH) {
      if (l == 0)
        xg_gemm<true><<<dim3(32, 16), 256, 0, stream>>>(emb, tok, wih_l, bih_l, bhh_l, XG, t0);
      else
        xg_gemm<false><<<dim3(32, 16), 256, 0, stream>>>(Y, nullptr, wih_l, bih_l, bhh_l, XG, t0);
      lstm_chunk<<<256, 256, 0, stream>>>(XG, whh_l, h0, h1, c, Y, flag, t0, l);
    }
  }
  cls_kernel<<<64, 64, 0, stream>>>(Y, Wcls, bcls, out);
}